// Round 9
// baseline (314.688 us; speedup 1.0000x reference)
//
#include <hip/hip_runtime.h>

// ---------------------------------------------------------------------------
// ConstraintViolationLoss: build x; sparse Ax via deterministic counting-sort.
// r9 split: streaming hist+product pass (gather hidden at high occupancy,
// bf16 products packed 2/u32) feeds a lean r7-style block-FIFO scatter that
// only routes (rows, prod16) -> (loc|bf16) records. LDS bucket accumulation,
// fused reduction to [penalty, mean_viol, max_viol, n_violated].
//
// History: r1/r4 fp32 global atomics = memory-side RMW (500MB). r2/r5 raw
// scattered stores = 0.9-1.0GB write-allocate. r6/r7 block-FIFO WC fixes
// bytes (WRITE ~= logical). r8 wave-private FIFO regressed (serial flush).
// r9: cut the FIFO pass from 283MB to 160MB by precomputing products.
// ---------------------------------------------------------------------------

#define BSHIFT 14
#define BROWS  (1 << BSHIFT)     // 16384 rows/bucket
#define NBUCK_MAX 32
#define CHUNK 8192               // edges per chunk (one block each)
#define ROUNDS (CHUNK / 1024)    // 8 rounds: 256 threads x 4 edges
#define BUF 128                  // FIFO depth per bucket (block-shared)
#define THRESH 48                // flush threshold
#define SPLIT 16                 // accumulate blocks per bucket

typedef int      iv4 __attribute__((ext_vector_type(4)));
typedef float    fv4 __attribute__((ext_vector_type(4)));
typedef unsigned uv2 __attribute__((ext_vector_type(2)));
typedef unsigned uv4 __attribute__((ext_vector_type(4)));

__device__ inline unsigned bf16bits(float v) {
    unsigned f = __float_as_uint(v);
    return (f + 0x7FFFu + ((f >> 16) & 1u)) >> 16;   // RNE
}

// ------------------ K1: fused build-x (4 partitions) + acc zero -------------

__global__ __launch_bounds__(256) void k_build_x(
    const float* __restrict__ prob_bin, const int* __restrict__ idx_bin, int NB, int gBin,
    const float* __restrict__ logits, const float* __restrict__ offs,
    const int* __restrict__ idx_small, int NS, int gSml,
    const float* __restrict__ pred, const int* __restrict__ idx_large, int NL, int gLrg,
    const int* __restrict__ vt, const float* __restrict__ vf, int NV,
    float* __restrict__ x, float* __restrict__ acc)
{
    int blk = blockIdx.x, tid = threadIdx.x;
    if (blk == 0 && tid < 4) reinterpret_cast<unsigned*>(acc)[tid] = 0u;

    if (blk < gBin) {
        int i = blk * 256 + tid;
        if (i < NB) x[idx_bin[i]] = prob_bin[i];
        return;
    }
    blk -= gBin;
    if (blk < gSml) {
        int i = blk * 256 + tid;
        if (i < NS) {
            const fv4* lp = reinterpret_cast<const fv4*>(logits + (size_t)i * 16);
            fv4 v0 = lp[0], v1 = lp[1], v2 = lp[2], v3 = lp[3];
            float l[16] = {v0.x, v0.y, v0.z, v0.w, v1.x, v1.y, v1.z, v1.w,
                           v2.x, v2.y, v2.z, v2.w, v3.x, v3.y, v3.z, v3.w};
            float m = l[0];
#pragma unroll
            for (int j = 1; j < 16; ++j) m = fmaxf(m, l[j]);
            float s = 0.f, ws = 0.f;
#pragma unroll
            for (int j = 0; j < 16; ++j) {
                float e = expf(l[j] - m);
                s += e;
                ws += e * (float)j;
            }
            x[idx_small[i]] = ws / s + offs[i];
        }
        return;
    }
    blk -= gSml;
    if (blk < gLrg) {
        int i = blk * 256 + tid;
        if (i < NL) x[idx_large[i]] = pred[i];
        return;
    }
    blk -= gLrg;
    {
        int v = blk * 256 + tid;
        if (v < NV && vt[v] == 0) x[v] = vf[(size_t)v * 16 + 8];
    }
}

// ---- K2: per-chunk bucket histogram (+ bf16 products, packed 2/u32) --------

template <bool PROD>
__global__ __launch_bounds__(256) void k_hist_prod(const int* __restrict__ rows,
                                                   const int* __restrict__ cols,
                                                   const float* __restrict__ ef,
                                                   const float* __restrict__ x,
                                                   int* __restrict__ counts,
                                                   unsigned* __restrict__ prods,
                                                   int nchunks, int E, int nbuck) {
    __shared__ int h[4][NBUCK_MAX];
    int tid = threadIdx.x, chunk = blockIdx.x, wid = tid >> 6, lane = tid & 63;
    if (lane < NBUCK_MAX) h[wid][lane] = 0;
    __syncthreads();
    int e4max = E >> 2;
    int b4 = chunk * (CHUNK / 4);
#pragma unroll
    for (int k = 0; k < ROUNDS; ++k) {
        int i4 = b4 + k * 256 + tid;
        if (i4 < e4max) {
            iv4 r = __builtin_nontemporal_load(reinterpret_cast<const iv4*>(rows) + i4);
            atomicAdd(&h[wid][r.x >> BSHIFT], 1);
            atomicAdd(&h[wid][r.y >> BSHIFT], 1);
            atomicAdd(&h[wid][r.z >> BSHIFT], 1);
            atomicAdd(&h[wid][r.w >> BSHIFT], 1);
            if (PROD) {
                iv4 c = __builtin_nontemporal_load(reinterpret_cast<const iv4*>(cols) + i4);
                fv4 f = __builtin_nontemporal_load(reinterpret_cast<const fv4*>(ef) + i4);
                unsigned p01 = bf16bits(f.x * x[c.x]) | (bf16bits(f.y * x[c.y]) << 16);
                unsigned p23 = bf16bits(f.z * x[c.z]) | (bf16bits(f.w * x[c.w]) << 16);
                uv2 p = {p01, p23};
                __builtin_nontemporal_store(p, reinterpret_cast<uv2*>(prods) + i4);
            }
        }
    }
    if (chunk == 0 && tid < (E & 3)) {            // scalar tail -> chunk 0
        int e = (E & ~3) + tid;
        atomicAdd(&h[wid][rows[e] >> BSHIFT], 1);
        if (PROD)
            reinterpret_cast<unsigned short*>(prods)[e] =
                (unsigned short)bf16bits(ef[e] * x[cols[e]]);
    }
    __syncthreads();
    if (tid < nbuck)
        counts[(size_t)tid * nchunks + chunk] = h[0][tid] + h[1][tid] + h[2][tid] + h[3][tid];
}

// ---------- K3: per-bucket scan over chunks (two-tier, 1024 threads) --------

__global__ __launch_bounds__(1024) void k_scan(const int* __restrict__ counts,
                                               int* __restrict__ off,
                                               int* __restrict__ total, int nchunks) {
    int b = blockIdx.x;
    __shared__ int wtot[16];
    __shared__ int wbase[16];
    int tid = threadIdx.x, w = tid >> 6, lane = tid & 63;
    int seg = (nchunks + 15) >> 4;
    int lo = w * seg;
    int hi = lo + seg; if (hi > nchunks) hi = nchunks;
    const int* cb = counts + (size_t)b * nchunks;
    int* ob = off + (size_t)b * nchunks;
    int carry = 0;
    for (int i0 = lo; i0 < hi; i0 += 64) {
        int i = i0 + lane;
        int v = (i < hi) ? cb[i] : 0;
        int orig = v;
#pragma unroll
        for (int o = 1; o < 64; o <<= 1) {
            int t = __shfl_up(v, o, 64);
            if (lane >= o) v += t;
        }
        if (i < hi) ob[i] = carry + v - orig;
        carry += __shfl(v, 63, 64);
    }
    if (lane == 0) wtot[w] = carry;
    __syncthreads();
    if (tid == 0) {
        int s = 0;
        for (int k = 0; k < 16; ++k) { wbase[k] = s; s += wtot[k]; }
        total[b] = s;
    }
    __syncthreads();
    int add = wbase[w];
    if (add)
        for (int i = lo + lane; i < hi; i += 64) ob[i] += add;
}

// ---- K4: scatter, r7 block-shared FIFO, bases derived from total[] ---------

template <bool PROD>
__global__ __launch_bounds__(256) void k_scatter5(const int* __restrict__ rows,
                                                  const int* __restrict__ cols,
                                                  const float* __restrict__ ef,
                                                  const float* __restrict__ x,
                                                  const unsigned* __restrict__ prods,
                                                  const int* __restrict__ off,
                                                  const int* __restrict__ total,
                                                  unsigned* __restrict__ recs,
                                                  int nchunks, int E, int nbuck) {
    __shared__ unsigned bufr[NBUCK_MAX][BUF];   // 16KB
    __shared__ int fill[NBUCK_MAX];
    __shared__ int done[NBUCK_MAX];
    __shared__ int cbase[NBUCK_MAX];

    int tid = threadIdx.x, chunk = blockIdx.x, wid = tid >> 6, lane = tid & 63;
    if (tid < 32) {                                // padded bucket bases from total[]
        int t = (tid < nbuck) ? total[tid] : 0;
        int p = (t + 3) & ~3;
        int sc = p;
#pragma unroll
        for (int o = 1; o < 32; o <<= 1) {
            int u = __shfl_up(sc, o, 64);
            if (tid >= o) sc += u;
        }
        cbase[tid] = (sc - p) + ((tid < nbuck) ? off[(size_t)tid * nchunks + chunk] : 0);
        fill[tid] = 0;
        done[tid] = 0;
    }
    __syncthreads();

    int e4max = E >> 2;
    int b4 = chunk * (CHUNK / 4);

    iv4 r, c; fv4 f; uv2 p; bool v;
#define LOADK(k)                                                              \
    {   int i4 = b4 + (k) * 256 + tid;                                        \
        v = i4 < e4max;                                                       \
        if (v) {                                                              \
            r = __builtin_nontemporal_load(reinterpret_cast<const iv4*>(rows) + i4); \
            if (PROD) {                                                       \
                p = __builtin_nontemporal_load(reinterpret_cast<const uv2*>(prods) + i4); \
            } else {                                                          \
                c = __builtin_nontemporal_load(reinterpret_cast<const iv4*>(cols) + i4); \
                f = __builtin_nontemporal_load(reinterpret_cast<const fv4*>(ef) + i4);   \
            }                                                                 \
        } }

    LOADK(0)
    for (int k = 0; k < ROUNDS; ++k) {
        iv4 rr = r; iv4 cc = c; fv4 ff = f; uv2 pp = p; bool vv = v;
        if (k + 1 < ROUNDS) LOADK(k + 1)
        if (vv) {
            unsigned q[4];
            if (PROD) {
                q[0] = pp.x & 0xFFFFu; q[1] = pp.x >> 16;
                q[2] = pp.y & 0xFFFFu; q[3] = pp.y >> 16;
            } else {
                q[0] = bf16bits(ff.x * x[cc.x]);
                q[1] = bf16bits(ff.y * x[cc.y]);
                q[2] = bf16bits(ff.z * x[cc.z]);
                q[3] = bf16bits(ff.w * x[cc.w]);
            }
            int ra[4] = {rr.x, rr.y, rr.z, rr.w};
#pragma unroll
            for (int j = 0; j < 4; ++j) {
                int b = ra[j] >> BSHIFT;
                unsigned rec = ((unsigned)(ra[j] & (BROWS - 1)) << 16) | q[j];
                int pos = atomicAdd(&fill[b], 1);
                if (pos < BUF) bufr[b][pos] = rec;
                else recs[cbase[b] + done[b] + pos] = rec;   // rare spill
            }
        }
        if (k == ROUNDS - 1 && chunk == 0 && tid < (E & 3)) {
            int e = (E & ~3) + tid;
            int rrow = rows[e];
            unsigned q16 = PROD ? (unsigned)reinterpret_cast<const unsigned short*>(prods)[e]
                                : bf16bits(ef[e] * x[cols[e]]);
            int b = rrow >> BSHIFT;
            unsigned rec = ((unsigned)(rrow & (BROWS - 1)) << 16) | q16;
            int pos = atomicAdd(&fill[b], 1);
            if (pos < BUF) bufr[b][pos] = rec;
            else recs[cbase[b] + done[b] + pos] = rec;
        }
        __syncthreads();
        bool last = (k == ROUNDS - 1);
        for (int b = wid; b < nbuck; b += 4) {     // parallel flush across waves
            int fl = fill[b];
            if (fl == 0) continue;
            if (fl >= THRESH || last) {
                int n = fl < BUF ? fl : BUF;
                int g = cbase[b] + done[b];
                for (int j = lane; j < n; j += 64) recs[g + j] = bufr[b][j];
                if (lane == 0) { done[b] += fl; fill[b] = 0; }
            }
        }
        __syncthreads();
    }
#undef LOADK
}

// -------- K5: LDS bucket accumulate (uint4 loads, exact len) ----------------

__global__ __launch_bounds__(256) void k_accum(const unsigned* __restrict__ recs,
                                               const int* __restrict__ total,
                                               float* __restrict__ partial, int nbuck) {
    __shared__ float tile[BROWS];   // 64KB
    __shared__ int sb[2];           // lo, len
    int tid = threadIdx.x;
    int b = blockIdx.x / SPLIT, s = blockIdx.x % SPLIT;
    if (tid < 32) {
        int t = (tid < nbuck) ? total[tid] : 0;
        int pq = (t + 3) & ~3;
        int sc = pq;
#pragma unroll
        for (int o = 1; o < 32; o <<= 1) {
            int u = __shfl_up(sc, o, 64);
            if (tid >= o) sc += u;
        }
        if (tid == b) { sb[0] = sc - pq; sb[1] = t; }
    }
    fv4 z = {0.f, 0.f, 0.f, 0.f};
    for (int i = tid; i < BROWS / 4; i += 256) reinterpret_cast<fv4*>(tile)[i] = z;
    __syncthreads();
    int lo = sb[0], len = sb[1], hi = lo + len;
    int per = ((len + SPLIT - 1) / SPLIT + 3) & ~3;
    int s0 = lo + s * per;
    int s1 = s0 + per; if (s1 > hi) s1 = hi;
    int i = s0 + (tid << 2);
    for (; i + 3 < s1; i += 1024) {
        uv4 r = __builtin_nontemporal_load(reinterpret_cast<const uv4*>(recs + i));
        atomicAdd(&tile[r.x >> 16], __uint_as_float((r.x & 0xFFFFu) << 16));
        atomicAdd(&tile[r.y >> 16], __uint_as_float((r.y & 0xFFFFu) << 16));
        atomicAdd(&tile[r.z >> 16], __uint_as_float((r.z & 0xFFFFu) << 16));
        atomicAdd(&tile[r.w >> 16], __uint_as_float((r.w & 0xFFFFu) << 16));
    }
    if (i < s1)                                  // <=3 tail records
        for (int j = i; j < s1; ++j) {
            unsigned rr = recs[j];
            atomicAdd(&tile[rr >> 16], __uint_as_float((rr & 0xFFFFu) << 16));
        }
    __syncthreads();
    float* out = partial + ((size_t)blockIdx.x << BSHIFT);
    for (int j = tid; j < BROWS / 4; j += 256)
        __builtin_nontemporal_store(reinterpret_cast<const fv4*>(tile)[j],
                                    reinterpret_cast<fv4*>(out) + j);
}

// ------- K6: fold partials + bias + relu + reduce + ticketed finalize -------

__global__ __launch_bounds__(256) void k_reduce_fin(const float* __restrict__ partial,
                                                    const float* __restrict__ cf,
                                                    float* __restrict__ acc,
                                                    float* __restrict__ out,
                                                    int ncon, int nblocks) {
    float lsum = 0.f, lmax = 0.f;
    unsigned lcnt = 0;
    int stride = gridDim.x * blockDim.x;
    for (int c = blockIdx.x * blockDim.x + threadIdx.x; c < ncon; c += stride) {
        int b = c >> BSHIFT, i = c & (BROWS - 1);
        const float* p = partial + (((size_t)b * SPLIT) << BSHIFT) + i;
        float v = 0.f;
#pragma unroll
        for (int s = 0; s < SPLIT; ++s)
            v += __builtin_nontemporal_load(p + ((size_t)s << BSHIFT));
        v -= cf[(size_t)c * 8 + 1];
        v = v > 0.f ? v : 0.f;
        lsum += v;
        lmax = fmaxf(lmax, v);
        lcnt += (v > 1e-6f) ? 1u : 0u;
    }
#pragma unroll
    for (int o = 32; o > 0; o >>= 1) {
        lsum += __shfl_down(lsum, o);
        lmax = fmaxf(lmax, __shfl_down(lmax, o));
        lcnt += __shfl_down(lcnt, o);
    }
    __shared__ float ssum[4];
    __shared__ float smax[4];
    __shared__ unsigned scnt[4];
    int lane = threadIdx.x & 63, wid = threadIdx.x >> 6;
    if (lane == 0) { ssum[wid] = lsum; smax[wid] = lmax; scnt[wid] = lcnt; }
    __syncthreads();
    if (threadIdx.x == 0) {
        float bs = 0.f, bm = 0.f;
        unsigned bc = 0;
        for (int w = 0; w < 4; ++w) { bs += ssum[w]; bm = fmaxf(bm, smax[w]); bc += scnt[w]; }
        atomicAdd(&acc[0], bs);
        atomicMax(reinterpret_cast<unsigned*>(acc) + 1, __float_as_uint(bm));
        atomicAdd(reinterpret_cast<unsigned*>(acc) + 2, bc);
        __threadfence();
        unsigned t = atomicAdd(reinterpret_cast<unsigned*>(acc) + 3, 1u);
        if (t == (unsigned)(nblocks - 1)) {
            float sum   = atomicAdd(&acc[0], 0.f);
            unsigned mb = atomicMax(reinterpret_cast<unsigned*>(acc) + 1, 0u);
            unsigned ct = atomicAdd(reinterpret_cast<unsigned*>(acc) + 2, 0u);
            float mean = sum / (float)ncon;
            float mx = __uint_as_float(mb);
            out[0] = mean + 0.1f * mx;
            out[1] = mean;
            out[2] = mx;
            out[3] = (float)ct;
        }
    }
}

// ------------------- fallback: direct device-scope atomics ------------------

__global__ void k_edges(const float* __restrict__ ef, const int* __restrict__ rows,
                        const int* __restrict__ cols, const float* __restrict__ x,
                        float* __restrict__ Ax, int e4, int E) {
    int stride = gridDim.x * blockDim.x;
    int gid = blockIdx.x * blockDim.x + threadIdx.x;
    for (int i = gid; i < e4; i += stride) {
        fv4 f = reinterpret_cast<const fv4*>(ef)[i];
        iv4 r = reinterpret_cast<const iv4*>(rows)[i];
        iv4 c = reinterpret_cast<const iv4*>(cols)[i];
        atomicAdd(&Ax[r.x], f.x * x[c.x]);
        atomicAdd(&Ax[r.y], f.y * x[c.y]);
        atomicAdd(&Ax[r.z], f.z * x[c.z]);
        atomicAdd(&Ax[r.w], f.w * x[c.w]);
    }
    for (int e = e4 * 4 + gid; e < E; e += stride)
        atomicAdd(&Ax[rows[e]], ef[e] * x[cols[e]]);
}

__global__ void k_reduce_ax(const float* __restrict__ Ax, const float* __restrict__ cf,
                            float* __restrict__ acc, float* __restrict__ out,
                            int ncon, int nblocks) {
    float lsum = 0.f, lmax = 0.f;
    unsigned lcnt = 0;
    int stride = gridDim.x * blockDim.x;
    for (int c = blockIdx.x * blockDim.x + threadIdx.x; c < ncon; c += stride) {
        float v = Ax[c] - cf[(size_t)c * 8 + 1];
        v = v > 0.f ? v : 0.f;
        lsum += v;
        lmax = fmaxf(lmax, v);
        lcnt += (v > 1e-6f) ? 1u : 0u;
    }
#pragma unroll
    for (int o = 32; o > 0; o >>= 1) {
        lsum += __shfl_down(lsum, o);
        lmax = fmaxf(lmax, __shfl_down(lmax, o));
        lcnt += __shfl_down(lcnt, o);
    }
    __shared__ float ssum[4];
    __shared__ float smax[4];
    __shared__ unsigned scnt[4];
    int lane = threadIdx.x & 63, wid = threadIdx.x >> 6;
    if (lane == 0) { ssum[wid] = lsum; smax[wid] = lmax; scnt[wid] = lcnt; }
    __syncthreads();
    if (threadIdx.x == 0) {
        float bs = 0.f, bm = 0.f;
        unsigned bc = 0;
        for (int w = 0; w < 4; ++w) { bs += ssum[w]; bm = fmaxf(bm, smax[w]); bc += scnt[w]; }
        atomicAdd(&acc[0], bs);
        atomicMax(reinterpret_cast<unsigned*>(acc) + 1, __float_as_uint(bm));
        atomicAdd(reinterpret_cast<unsigned*>(acc) + 2, bc);
        __threadfence();
        unsigned t = atomicAdd(reinterpret_cast<unsigned*>(acc) + 3, 1u);
        if (t == (unsigned)(nblocks - 1)) {
            float sum   = atomicAdd(&acc[0], 0.f);
            unsigned mb = atomicMax(reinterpret_cast<unsigned*>(acc) + 1, 0u);
            unsigned ct = atomicAdd(reinterpret_cast<unsigned*>(acc) + 2, 0u);
            float mean = sum / (float)ncon;
            float mx = __uint_as_float(mb);
            out[0] = mean + 0.1f * mx;
            out[1] = mean;
            out[2] = mx;
            out[3] = (float)ct;
        }
    }
}

// ------------------------------ launcher -----------------------------------

extern "C" void kernel_launch(void* const* d_in, const int* in_sizes, int n_in,
                              void* d_out, int out_size, void* d_ws, size_t ws_size,
                              hipStream_t stream) {
    const float* prob_bin     = (const float*)d_in[0];
    const float* logits_small = (const float*)d_in[1];
    const float* offs_small   = (const float*)d_in[2];
    const float* pred_large   = (const float*)d_in[3];
    const float* edge_feat    = (const float*)d_in[4];
    const float* cons_feat    = (const float*)d_in[5];
    const float* var_feat     = (const float*)d_in[6];
    const int*   idx_bin      = (const int*)d_in[7];
    const int*   idx_small    = (const int*)d_in[8];
    const int*   idx_large    = (const int*)d_in[9];
    const int*   var_types    = (const int*)d_in[10];
    const int*   edge_indices = (const int*)d_in[11];

    const int NB    = in_sizes[0];
    const int NS    = in_sizes[2];
    const int NL    = in_sizes[3];
    const int E     = in_sizes[4];
    const int NCON  = in_sizes[5] / 8;
    const int NVARS = in_sizes[10];

    const int* rows = edge_indices;
    const int* cols = edge_indices + E;

    const int nbuck   = (NCON + BROWS - 1) >> BSHIFT;
    const int nchunks = (E + CHUNK - 1) / CHUNK;

    // ws layout (256B-aligned): x | recs | partial | counts | off | total | acc | [prods]
    char* w = (char*)d_ws;
    size_t o = 0;
    auto take = [&](size_t bytes) -> char* {
        char* p = w + o;
        o = (o + bytes + 255) & ~(size_t)255;
        return p;
    };
    float*    x       = (float*)take((size_t)NVARS * 4);
    unsigned* recs    = (unsigned*)take((size_t)(E + 4 * NBUCK_MAX) * 4);
    float*    partial = (float*)take((size_t)nbuck * SPLIT * BROWS * 4);
    int*      counts  = (int*)take((size_t)nbuck * nchunks * 4);
    int*      off     = (int*)take((size_t)nbuck * nchunks * 4);
    int*      total   = (int*)take((size_t)nbuck * 4);
    float*    acc     = (float*)take(32);
    size_t needB = o;
    unsigned* prods   = (unsigned*)take((size_t)(E / 2 + 8) * 4);
    size_t needA = o;

    const int B = 256;
    bool tierA = (ws_size >= needA) && (nbuck <= NBUCK_MAX);
    bool tierB = (ws_size >= needB) && (nbuck <= NBUCK_MAX);

    if (tierA || tierB) {
        const int gBin = (NB + B - 1) / B;
        const int gSml = (NS + B - 1) / B;
        const int gLrg = (NL + B - 1) / B;
        const int gCnt = (NVARS + B - 1) / B;

        k_build_x<<<gBin + gSml + gLrg + gCnt, B, 0, stream>>>(
            prob_bin, idx_bin, NB, gBin,
            logits_small, offs_small, idx_small, NS, gSml,
            pred_large, idx_large, NL, gLrg,
            var_types, var_feat, NVARS, x, acc);

        if (tierA)
            k_hist_prod<true><<<nchunks, B, 0, stream>>>(rows, cols, edge_feat, x,
                                                         counts, prods, nchunks, E, nbuck);
        else
            k_hist_prod<false><<<nchunks, B, 0, stream>>>(rows, cols, edge_feat, x,
                                                          counts, prods, nchunks, E, nbuck);

        k_scan<<<nbuck, 1024, 0, stream>>>(counts, off, total, nchunks);

        if (tierA)
            k_scatter5<true><<<nchunks, B, 0, stream>>>(rows, cols, edge_feat, x, prods,
                                                        off, total, recs, nchunks, E, nbuck);
        else
            k_scatter5<false><<<nchunks, B, 0, stream>>>(rows, cols, edge_feat, x, prods,
                                                         off, total, recs, nchunks, E, nbuck);

        k_accum<<<nbuck * SPLIT, B, 0, stream>>>(recs, total, partial, nbuck);
        const int rblocks = 1024;
        k_reduce_fin<<<rblocks, B, 0, stream>>>(partial, cons_feat, acc, (float*)d_out,
                                                NCON, rblocks);
    } else {
        // fallback: direct device-scope atomics
        float* accf = (float*)((char*)d_ws + (size_t)NVARS * 4);
        float* Ax   = accf + 8;
        (void)hipMemsetAsync(accf, 0, (size_t)(8 + NCON) * sizeof(float), stream);
        const int gBin = (NB + B - 1) / B;
        const int gSml = (NS + B - 1) / B;
        const int gLrg = (NL + B - 1) / B;
        const int gCnt = (NVARS + B - 1) / B;
        k_build_x<<<gBin + gSml + gLrg + gCnt, B, 0, stream>>>(
            prob_bin, idx_bin, NB, gBin,
            logits_small, offs_small, idx_small, NS, gSml,
            pred_large, idx_large, NL, gLrg,
            var_types, var_feat, NVARS, x, accf);
        k_edges<<<2048, B, 0, stream>>>(edge_feat, rows, cols, x, Ax, E / 4, E);
        k_reduce_ax<<<1024, B, 0, stream>>>(Ax, cons_feat, accf, (float*)d_out, NCON, 1024);
    }
}

// Round 10
// 274.376 us; speedup vs baseline: 1.1469x; 1.1469x over previous
//
#include <hip/hip_runtime.h>

// ---------------------------------------------------------------------------
// ConstraintViolationLoss: build x (bf16); sparse Ax via deterministic
// counting-sort with block-shared LDS write-combining FIFOs, fused
// gather+product (x kept bf16 so it stays L2-resident against the NT edge
// streams), NT burst flushes; LDS bucket accumulation; fused reduction to
// [penalty, mean_viol, max_viol, n_violated].
//
// History: r1/r4 fp32 global atomics = memory-side RMW (500MB, scope
// ignored). r2/r5 raw scattered stores = 0.9-1GB write-allocate. r6/r7
// block-FIFO write-combining fixes bytes. r9 isolated the bottleneck: the
// 16M x[col] gathers miss L2 (4MB f32 x thrashed by streams) -> ~1GB of
// 64B-line L3 traffic ~= 100us in whichever kernel hosts the gather.
// r10: bf16 x (2MB, L2-resident), re-fused product, NT flushes, SPLIT 8.
// ---------------------------------------------------------------------------

#define BSHIFT 14
#define BROWS  (1 << BSHIFT)     // 16384 rows/bucket
#define NBUCK_MAX 32
#define CHUNK 8192               // edges per chunk (one block each)
#define ROUNDS (CHUNK / 1024)    // 8 rounds: 256 threads x 4 edges
#define BUF 128                  // FIFO depth per bucket (block-shared)
#define THRESH 48                // flush threshold
#define SPLIT 8                  // accumulate blocks per bucket

typedef int      iv4 __attribute__((ext_vector_type(4)));
typedef float    fv4 __attribute__((ext_vector_type(4)));
typedef unsigned uv4 __attribute__((ext_vector_type(4)));

__device__ inline unsigned bf16bits(float v) {
    unsigned f = __float_as_uint(v);
    return (f + 0x7FFFu + ((f >> 16) & 1u)) >> 16;   // RNE
}
__device__ inline float bf16val(unsigned bits) {
    return __uint_as_float(bits << 16);
}

// ---------- K1: fused edge histogram + build-x(bf16) + acc zero -------------

__global__ __launch_bounds__(256) void k_build_hist(
    const int* __restrict__ rows, int* __restrict__ counts, int nchunks, int gHist,
    const float* __restrict__ prob_bin, const int* __restrict__ idx_bin, int NB, int gBin,
    const float* __restrict__ logits, const float* __restrict__ offs,
    const int* __restrict__ idx_small, int NS, int gSml,
    const float* __restrict__ pred, const int* __restrict__ idx_large, int NL, int gLrg,
    const int* __restrict__ vt, const float* __restrict__ vf, int NV,
    int E, int nbuck, unsigned short* __restrict__ xb, float* __restrict__ acc)
{
    int blk = blockIdx.x, tid = threadIdx.x;
    if (blk == 0 && tid < 4) reinterpret_cast<unsigned*>(acc)[tid] = 0u;

    if (blk < gHist) {                        // ---- histogram chunk
        __shared__ int h[4][NBUCK_MAX];
        int wid = tid >> 6, lane = tid & 63;
        if (lane < NBUCK_MAX) h[wid][lane] = 0;
        __syncthreads();
        int e4max = E >> 2;
        int b4 = blk * (CHUNK / 4);
#pragma unroll
        for (int k = 0; k < ROUNDS; ++k) {
            int i4 = b4 + k * 256 + tid;
            if (i4 < e4max) {
                iv4 r = __builtin_nontemporal_load(reinterpret_cast<const iv4*>(rows) + i4);
                atomicAdd(&h[wid][r.x >> BSHIFT], 1);
                atomicAdd(&h[wid][r.y >> BSHIFT], 1);
                atomicAdd(&h[wid][r.z >> BSHIFT], 1);
                atomicAdd(&h[wid][r.w >> BSHIFT], 1);
            }
        }
        if (blk == 0 && tid < (E & 3))
            atomicAdd(&h[wid][rows[(E & ~3) + tid] >> BSHIFT], 1);
        __syncthreads();
        if (tid < nbuck)
            counts[(size_t)tid * nchunks + blk] =
                h[0][tid] + h[1][tid] + h[2][tid] + h[3][tid];
        return;
    }
    blk -= gHist;
    if (blk < gBin) {                         // ---- binary scatter
        int i = blk * 256 + tid;
        if (i < NB) xb[idx_bin[i]] = (unsigned short)bf16bits(prob_bin[i]);
        return;
    }
    blk -= gBin;
    if (blk < gSml) {                         // ---- small-int softmax E[]
        int i = blk * 256 + tid;
        if (i < NS) {
            const fv4* lp = reinterpret_cast<const fv4*>(logits + (size_t)i * 16);
            fv4 v0 = lp[0], v1 = lp[1], v2 = lp[2], v3 = lp[3];
            float l[16] = {v0.x, v0.y, v0.z, v0.w, v1.x, v1.y, v1.z, v1.w,
                           v2.x, v2.y, v2.z, v2.w, v3.x, v3.y, v3.z, v3.w};
            float m = l[0];
#pragma unroll
            for (int j = 1; j < 16; ++j) m = fmaxf(m, l[j]);
            float s = 0.f, ws = 0.f;
#pragma unroll
            for (int j = 0; j < 16; ++j) {
                float e = expf(l[j] - m);
                s += e;
                ws += e * (float)j;
            }
            xb[idx_small[i]] = (unsigned short)bf16bits(ws / s + offs[i]);
        }
        return;
    }
    blk -= gSml;
    if (blk < gLrg) {                         // ---- large-int scatter
        int i = blk * 256 + tid;
        if (i < NL) xb[idx_large[i]] = (unsigned short)bf16bits(pred[i]);
        return;
    }
    blk -= gLrg;
    {                                         // ---- continuous override
        int v = blk * 256 + tid;
        if (v < NV && vt[v] == 0) xb[v] = (unsigned short)bf16bits(vf[(size_t)v * 16 + 8]);
    }
}

// ---------- K2: per-bucket scan over chunks (two-tier, 1024 threads) --------

__global__ __launch_bounds__(1024) void k_scan(const int* __restrict__ counts,
                                               int* __restrict__ off,
                                               int* __restrict__ total, int nchunks) {
    int b = blockIdx.x;
    __shared__ int wtot[16];
    __shared__ int wbase[16];
    int tid = threadIdx.x, w = tid >> 6, lane = tid & 63;
    int seg = (nchunks + 15) >> 4;
    int lo = w * seg;
    int hi = lo + seg; if (hi > nchunks) hi = nchunks;
    const int* cb = counts + (size_t)b * nchunks;
    int* ob = off + (size_t)b * nchunks;
    int carry = 0;
    for (int i0 = lo; i0 < hi; i0 += 64) {
        int i = i0 + lane;
        int v = (i < hi) ? cb[i] : 0;
        int orig = v;
#pragma unroll
        for (int o = 1; o < 64; o <<= 1) {
            int t = __shfl_up(v, o, 64);
            if (lane >= o) v += t;
        }
        if (i < hi) ob[i] = carry + v - orig;
        carry += __shfl(v, 63, 64);
    }
    if (lane == 0) wtot[w] = carry;
    __syncthreads();
    if (tid == 0) {
        int s = 0;
        for (int k = 0; k < 16; ++k) { wbase[k] = s; s += wtot[k]; }
        total[b] = s;
    }
    __syncthreads();
    int add = wbase[w];
    if (add)
        for (int i = lo + lane; i < hi; i += 64) ob[i] += add;
}

// ---- K3: fused scatter: NT streams + bf16-x gather (prefetched) + FIFO -----

__global__ __launch_bounds__(256) void k_scatter6(const int* __restrict__ rows,
                                                  const int* __restrict__ cols,
                                                  const float* __restrict__ ef,
                                                  const unsigned short* __restrict__ xb,
                                                  const int* __restrict__ off,
                                                  const int* __restrict__ total,
                                                  unsigned* __restrict__ recs,
                                                  int nchunks, int E, int nbuck) {
    __shared__ unsigned bufr[NBUCK_MAX][BUF];   // 16KB
    __shared__ int fill[NBUCK_MAX];
    __shared__ int done[NBUCK_MAX];
    __shared__ int cbase[NBUCK_MAX];

    int tid = threadIdx.x, chunk = blockIdx.x, wid = tid >> 6, lane = tid & 63;
    if (tid < 32) {                             // padded bucket bases from total[]
        int t = (tid < nbuck) ? total[tid] : 0;
        int p = (t + 3) & ~3;
        int sc = p;
#pragma unroll
        for (int o = 1; o < 32; o <<= 1) {
            int u = __shfl_up(sc, o, 64);
            if (tid >= o) sc += u;
        }
        cbase[tid] = (sc - p) + ((tid < nbuck) ? off[(size_t)tid * nchunks + chunk] : 0);
        fill[tid] = 0;
        done[tid] = 0;
    }
    __syncthreads();

    int e4max = E >> 2;
    int b4 = chunk * (CHUNK / 4);

    iv4 rA, cA; fv4 fA; bool vA;
    iv4 rB, cB; fv4 fB; bool vB;
    unsigned gA0, gA1, gA2, gA3, gB0, gB1, gB2, gB3;

#define LOADK(k, R, C, F, V)                                                   \
    {   int i4 = b4 + (k) * 256 + tid;                                         \
        V = i4 < e4max;                                                        \
        if (V) {                                                               \
            R = __builtin_nontemporal_load(reinterpret_cast<const iv4*>(rows) + i4); \
            C = __builtin_nontemporal_load(reinterpret_cast<const iv4*>(cols) + i4); \
            F = __builtin_nontemporal_load(reinterpret_cast<const fv4*>(ef) + i4);   \
        } }
#define GATHK(C, V, G0, G1, G2, G3)                                            \
    if (V) { G0 = xb[C.x]; G1 = xb[C.y]; G2 = xb[C.z]; G3 = xb[C.w]; }

    LOADK(0, rA, cA, fA, vA)
    GATHK(cA, vA, gA0, gA1, gA2, gA3)

    for (int k = 0; k < ROUNDS; ++k) {
        if (k + 1 < ROUNDS) {                   // prefetch next round
            LOADK(k + 1, rB, cB, fB, vB)
            GATHK(cB, vB, gB0, gB1, gB2, gB3)
        }
        if (vA) {
            unsigned q[4] = {bf16bits(fA.x * bf16val(gA0)),
                             bf16bits(fA.y * bf16val(gA1)),
                             bf16bits(fA.z * bf16val(gA2)),
                             bf16bits(fA.w * bf16val(gA3))};
            int ra[4] = {rA.x, rA.y, rA.z, rA.w};
#pragma unroll
            for (int j = 0; j < 4; ++j) {
                int b = ra[j] >> BSHIFT;
                unsigned rec = ((unsigned)(ra[j] & (BROWS - 1)) << 16) | q[j];
                int pos = atomicAdd(&fill[b], 1);
                if (pos < BUF) bufr[b][pos] = rec;
                else recs[cbase[b] + done[b] + pos] = rec;   // rare spill
            }
        }
        if (k == ROUNDS - 1 && chunk == 0 && tid < (E & 3)) {   // scalar tail
            int e = (E & ~3) + tid;
            int rrow = rows[e];
            unsigned rec = ((unsigned)(rrow & (BROWS - 1)) << 16)
                         | bf16bits(ef[e] * bf16val(xb[cols[e]]));
            int b = rrow >> BSHIFT;
            int pos = atomicAdd(&fill[b], 1);
            if (pos < BUF) bufr[b][pos] = rec;
            else recs[cbase[b] + done[b] + pos] = rec;
        }
        __syncthreads();
        bool last = (k == ROUNDS - 1);
        for (int b = wid; b < nbuck; b += 4) {  // parallel flush across waves
            int fl = fill[b];
            if (fl == 0) continue;
            if (fl >= THRESH || last) {
                int n = fl < BUF ? fl : BUF;
                int g = cbase[b] + done[b];
                for (int j = lane; j < n; j += 64)
                    __builtin_nontemporal_store(bufr[b][j], recs + g + j);
                if (lane == 0) { done[b] += fl; fill[b] = 0; }
            }
        }
        __syncthreads();
        rA = rB; cA = cB; fA = fB; vA = vB;
        gA0 = gB0; gA1 = gB1; gA2 = gB2; gA3 = gB3;
    }
#undef LOADK
#undef GATHK
}

// -------- K4: LDS bucket accumulate (uint4 loads, exact len) ----------------

__global__ __launch_bounds__(256) void k_accum(const unsigned* __restrict__ recs,
                                               const int* __restrict__ total,
                                               float* __restrict__ partial, int nbuck) {
    __shared__ float tile[BROWS];   // 64KB
    __shared__ int sb[2];           // lo, len
    int tid = threadIdx.x;
    int b = blockIdx.x / SPLIT, s = blockIdx.x % SPLIT;
    if (tid < 32) {
        int t = (tid < nbuck) ? total[tid] : 0;
        int pq = (t + 3) & ~3;
        int sc = pq;
#pragma unroll
        for (int o = 1; o < 32; o <<= 1) {
            int u = __shfl_up(sc, o, 64);
            if (tid >= o) sc += u;
        }
        if (tid == b) { sb[0] = sc - pq; sb[1] = t; }
    }
    fv4 z = {0.f, 0.f, 0.f, 0.f};
    for (int i = tid; i < BROWS / 4; i += 256) reinterpret_cast<fv4*>(tile)[i] = z;
    __syncthreads();
    int lo = sb[0], len = sb[1], hi = lo + len;
    int per = ((len + SPLIT - 1) / SPLIT + 3) & ~3;
    int s0 = lo + s * per;
    int s1 = s0 + per; if (s1 > hi) s1 = hi;
    int i = s0 + (tid << 2);
    for (; i + 3 < s1; i += 1024) {
        uv4 r = __builtin_nontemporal_load(reinterpret_cast<const uv4*>(recs + i));
        atomicAdd(&tile[r.x >> 16], __uint_as_float((r.x & 0xFFFFu) << 16));
        atomicAdd(&tile[r.y >> 16], __uint_as_float((r.y & 0xFFFFu) << 16));
        atomicAdd(&tile[r.z >> 16], __uint_as_float((r.z & 0xFFFFu) << 16));
        atomicAdd(&tile[r.w >> 16], __uint_as_float((r.w & 0xFFFFu) << 16));
    }
    if (i < s1)
        for (int j = i; j < s1; ++j) {
            unsigned rr = recs[j];
            atomicAdd(&tile[rr >> 16], __uint_as_float((rr & 0xFFFFu) << 16));
        }
    __syncthreads();
    float* out = partial + ((size_t)blockIdx.x << BSHIFT);
    for (int j = tid; j < BROWS / 4; j += 256)
        __builtin_nontemporal_store(reinterpret_cast<const fv4*>(tile)[j],
                                    reinterpret_cast<fv4*>(out) + j);
}

// ------- K5: fold partials + bias + relu + reduce + ticketed finalize -------

__global__ __launch_bounds__(256) void k_reduce_fin(const float* __restrict__ partial,
                                                    const float* __restrict__ cf,
                                                    float* __restrict__ acc,
                                                    float* __restrict__ out,
                                                    int ncon, int nblocks) {
    float lsum = 0.f, lmax = 0.f;
    unsigned lcnt = 0;
    int stride = gridDim.x * blockDim.x;
    for (int c = blockIdx.x * blockDim.x + threadIdx.x; c < ncon; c += stride) {
        int b = c >> BSHIFT, i = c & (BROWS - 1);
        const float* p = partial + (((size_t)b * SPLIT) << BSHIFT) + i;
        float v = 0.f;
#pragma unroll
        for (int s = 0; s < SPLIT; ++s)
            v += __builtin_nontemporal_load(p + ((size_t)s << BSHIFT));
        v -= cf[(size_t)c * 8 + 1];
        v = v > 0.f ? v : 0.f;
        lsum += v;
        lmax = fmaxf(lmax, v);
        lcnt += (v > 1e-6f) ? 1u : 0u;
    }
#pragma unroll
    for (int o = 32; o > 0; o >>= 1) {
        lsum += __shfl_down(lsum, o);
        lmax = fmaxf(lmax, __shfl_down(lmax, o));
        lcnt += __shfl_down(lcnt, o);
    }
    __shared__ float ssum[4];
    __shared__ float smax[4];
    __shared__ unsigned scnt[4];
    int lane = threadIdx.x & 63, wid = threadIdx.x >> 6;
    if (lane == 0) { ssum[wid] = lsum; smax[wid] = lmax; scnt[wid] = lcnt; }
    __syncthreads();
    if (threadIdx.x == 0) {
        float bs = 0.f, bm = 0.f;
        unsigned bc = 0;
        for (int w = 0; w < 4; ++w) { bs += ssum[w]; bm = fmaxf(bm, smax[w]); bc += scnt[w]; }
        atomicAdd(&acc[0], bs);
        atomicMax(reinterpret_cast<unsigned*>(acc) + 1, __float_as_uint(bm));
        atomicAdd(reinterpret_cast<unsigned*>(acc) + 2, bc);
        __threadfence();
        unsigned t = atomicAdd(reinterpret_cast<unsigned*>(acc) + 3, 1u);
        if (t == (unsigned)(nblocks - 1)) {
            float sum   = atomicAdd(&acc[0], 0.f);
            unsigned mb = atomicMax(reinterpret_cast<unsigned*>(acc) + 1, 0u);
            unsigned ct = atomicAdd(reinterpret_cast<unsigned*>(acc) + 2, 0u);
            float mean = sum / (float)ncon;
            float mx = __uint_as_float(mb);
            out[0] = mean + 0.1f * mx;
            out[1] = mean;
            out[2] = mx;
            out[3] = (float)ct;
        }
    }
}

// ------------------- fallback: direct device-scope atomics ------------------

__global__ void k_edges(const float* __restrict__ ef, const int* __restrict__ rows,
                        const int* __restrict__ cols, const unsigned short* __restrict__ xb,
                        float* __restrict__ Ax, int e4, int E) {
    int stride = gridDim.x * blockDim.x;
    int gid = blockIdx.x * blockDim.x + threadIdx.x;
    for (int i = gid; i < e4; i += stride) {
        fv4 f = reinterpret_cast<const fv4*>(ef)[i];
        iv4 r = reinterpret_cast<const iv4*>(rows)[i];
        iv4 c = reinterpret_cast<const iv4*>(cols)[i];
        atomicAdd(&Ax[r.x], f.x * bf16val(xb[c.x]));
        atomicAdd(&Ax[r.y], f.y * bf16val(xb[c.y]));
        atomicAdd(&Ax[r.z], f.z * bf16val(xb[c.z]));
        atomicAdd(&Ax[r.w], f.w * bf16val(xb[c.w]));
    }
    for (int e = e4 * 4 + gid; e < E; e += stride)
        atomicAdd(&Ax[rows[e]], ef[e] * bf16val(xb[cols[e]]));
}

__global__ void k_reduce_ax(const float* __restrict__ Ax, const float* __restrict__ cf,
                            float* __restrict__ acc, float* __restrict__ out,
                            int ncon, int nblocks) {
    float lsum = 0.f, lmax = 0.f;
    unsigned lcnt = 0;
    int stride = gridDim.x * blockDim.x;
    for (int c = blockIdx.x * blockDim.x + threadIdx.x; c < ncon; c += stride) {
        float v = Ax[c] - cf[(size_t)c * 8 + 1];
        v = v > 0.f ? v : 0.f;
        lsum += v;
        lmax = fmaxf(lmax, v);
        lcnt += (v > 1e-6f) ? 1u : 0u;
    }
#pragma unroll
    for (int o = 32; o > 0; o >>= 1) {
        lsum += __shfl_down(lsum, o);
        lmax = fmaxf(lmax, __shfl_down(lmax, o));
        lcnt += __shfl_down(lcnt, o);
    }
    __shared__ float ssum[4];
    __shared__ float smax[4];
    __shared__ unsigned scnt[4];
    int lane = threadIdx.x & 63, wid = threadIdx.x >> 6;
    if (lane == 0) { ssum[wid] = lsum; smax[wid] = lmax; scnt[wid] = lcnt; }
    __syncthreads();
    if (threadIdx.x == 0) {
        float bs = 0.f, bm = 0.f;
        unsigned bc = 0;
        for (int w = 0; w < 4; ++w) { bs += ssum[w]; bm = fmaxf(bm, smax[w]); bc += scnt[w]; }
        atomicAdd(&acc[0], bs);
        atomicMax(reinterpret_cast<unsigned*>(acc) + 1, __float_as_uint(bm));
        atomicAdd(reinterpret_cast<unsigned*>(acc) + 2, bc);
        __threadfence();
        unsigned t = atomicAdd(reinterpret_cast<unsigned*>(acc) + 3, 1u);
        if (t == (unsigned)(nblocks - 1)) {
            float sum   = atomicAdd(&acc[0], 0.f);
            unsigned mb = atomicMax(reinterpret_cast<unsigned*>(acc) + 1, 0u);
            unsigned ct = atomicAdd(reinterpret_cast<unsigned*>(acc) + 2, 0u);
            float mean = sum / (float)ncon;
            float mx = __uint_as_float(mb);
            out[0] = mean + 0.1f * mx;
            out[1] = mean;
            out[2] = mx;
            out[3] = (float)ct;
        }
    }
}

// ------------------------------ launcher -----------------------------------

extern "C" void kernel_launch(void* const* d_in, const int* in_sizes, int n_in,
                              void* d_out, int out_size, void* d_ws, size_t ws_size,
                              hipStream_t stream) {
    const float* prob_bin     = (const float*)d_in[0];
    const float* logits_small = (const float*)d_in[1];
    const float* offs_small   = (const float*)d_in[2];
    const float* pred_large   = (const float*)d_in[3];
    const float* edge_feat    = (const float*)d_in[4];
    const float* cons_feat    = (const float*)d_in[5];
    const float* var_feat     = (const float*)d_in[6];
    const int*   idx_bin      = (const int*)d_in[7];
    const int*   idx_small    = (const int*)d_in[8];
    const int*   idx_large    = (const int*)d_in[9];
    const int*   var_types    = (const int*)d_in[10];
    const int*   edge_indices = (const int*)d_in[11];

    const int NB    = in_sizes[0];
    const int NS    = in_sizes[2];
    const int NL    = in_sizes[3];
    const int E     = in_sizes[4];
    const int NCON  = in_sizes[5] / 8;
    const int NVARS = in_sizes[10];

    const int* rows = edge_indices;
    const int* cols = edge_indices + E;

    const int nbuck   = (NCON + BROWS - 1) >> BSHIFT;
    const int nchunks = (E + CHUNK - 1) / CHUNK;

    // ws layout (256B-aligned): xb | recs | partial | counts | off | total | acc
    char* w = (char*)d_ws;
    size_t o = 0;
    auto take = [&](size_t bytes) -> char* {
        char* p = w + o;
        o = (o + bytes + 255) & ~(size_t)255;
        return p;
    };
    unsigned short* xb = (unsigned short*)take((size_t)NVARS * 2);
    unsigned* recs     = (unsigned*)take((size_t)(E + 4 * NBUCK_MAX) * 4);
    float*    partial  = (float*)take((size_t)nbuck * SPLIT * BROWS * 4);
    int*      counts   = (int*)take((size_t)nbuck * nchunks * 4);
    int*      off      = (int*)take((size_t)nbuck * nchunks * 4);
    int*      total    = (int*)take((size_t)nbuck * 4);
    float*    acc      = (float*)take(32);
    size_t need = o;

    const int B = 256;
    bool sorted_path = (ws_size >= need) && (nbuck <= NBUCK_MAX);

    const int gBin = (NB + B - 1) / B;
    const int gSml = (NS + B - 1) / B;
    const int gLrg = (NL + B - 1) / B;
    const int gCnt = (NVARS + B - 1) / B;

    if (sorted_path) {
        k_build_hist<<<nchunks + gBin + gSml + gLrg + gCnt, B, 0, stream>>>(
            rows, counts, nchunks, nchunks,
            prob_bin, idx_bin, NB, gBin,
            logits_small, offs_small, idx_small, NS, gSml,
            pred_large, idx_large, NL, gLrg,
            var_types, var_feat, NVARS,
            E, nbuck, xb, acc);
        k_scan<<<nbuck, 1024, 0, stream>>>(counts, off, total, nchunks);
        k_scatter6<<<nchunks, B, 0, stream>>>(rows, cols, edge_feat, xb, off, total,
                                              recs, nchunks, E, nbuck);
        k_accum<<<nbuck * SPLIT, B, 0, stream>>>(recs, total, partial, nbuck);
        const int rblocks = 1024;
        k_reduce_fin<<<rblocks, B, 0, stream>>>(partial, cons_feat, acc, (float*)d_out,
                                                NCON, rblocks);
    } else {
        // fallback: direct device-scope atomics (xb + Ax after it)
        float* accf = (float*)((char*)d_ws + (((size_t)NVARS * 2 + 255) & ~(size_t)255));
        float* Ax   = accf + 8;
        (void)hipMemsetAsync(accf, 0, (size_t)(8 + NCON) * sizeof(float), stream);
        k_build_hist<<<gBin + gSml + gLrg + gCnt, B, 0, stream>>>(
            rows, counts, nchunks, 0,
            prob_bin, idx_bin, NB, gBin,
            logits_small, offs_small, idx_small, NS, gSml,
            pred_large, idx_large, NL, gLrg,
            var_types, var_feat, NVARS,
            E, nbuck, xb, accf);
        k_edges<<<2048, B, 0, stream>>>(edge_feat, rows, cols, xb, Ax, E / 4, E);
        k_reduce_ax<<<1024, B, 0, stream>>>(Ax, cons_feat, accf, (float*)d_out, NCON, 1024);
    }
}